// Round 2
// baseline (1305.416 us; speedup 1.0000x reference)
//
#include <hip/hip_runtime.h>
#include <math.h>

#define BM 128
#define BN 256
#define BK 16
#define ASTRIDE 188          // 16 row-groups at stride 12 floats (15*12+8): breaks A-read bank aliasing
#define EPSV 1e-12f
#define NEG_INF_V -1000000000.0f
#define NBINS 2048
#define SCAP 2048
#define TAU 0.10f            // candidate threshold; correctness guarded by count>=K check + fallback

// ---------------- normalize x rows (one wave per row) ----------------
__global__ void xnorm_kernel(const float* __restrict__ x, float* __restrict__ xn, int D) {
    int row = blockIdx.x;
    int lane = threadIdx.x;          // 64 lanes
    const float4* xr = (const float4*)(x + (size_t)row * D);
    float4* xo = (float4*)(xn + (size_t)row * D);
    int per = (D / 4) / 64;          // D=512 -> 2
    float ss = 0.f;
    float4 v[4];
    for (int i = 0; i < per; ++i) {
        float4 t = xr[lane * per + i];
        v[i] = t;
        ss += t.x * t.x + t.y * t.y + t.z * t.z + t.w * t.w;
    }
    for (int off = 32; off >= 1; off >>= 1) ss += __shfl_xor(ss, off);
    float denom = fmaxf(sqrtf(ss), EPSV);
    for (int i = 0; i < per; ++i) {
        float4 t = v[i];
        t.x /= denom; t.y /= denom; t.z /= denom; t.w /= denom;
        xo[lane * per + i] = t;
    }
}

// ---------------- key inverse norms (one wave per key row) ----------------
__global__ void kinv_kernel(const float* __restrict__ keys, float* __restrict__ kinv,
                            int M, int D) {
    int wave = threadIdx.x >> 6;
    int lane = threadIdx.x & 63;
    int row = blockIdx.x * 4 + wave;
    if (row >= M) return;
    const float4* kr = (const float4*)(keys + (size_t)row * D);
    int per = (D / 4) / 64;          // 2
    float ss = 0.f;
    for (int i = 0; i < per; ++i) {
        float4 t = kr[lane * per + i];
        ss += t.x * t.x + t.y * t.y + t.z * t.z + t.w * t.w;
    }
    for (int off = 32; off >= 1; off >>= 1) ss += __shfl_xor(ss, off);
    if (lane == 0) kinv[row] = 1.0f / fmaxf(sqrtf(ss), EPSV);
}

// ---------------- fp32 SGEMM 128x256 tile, 8x16/thread + fused candidate collect ----------------
__global__ __launch_bounds__(256, 2)
void gemm_kernel(const float* __restrict__ xn, const float* __restrict__ keys,
                 const float* __restrict__ kinv, const int* __restrict__ values,
                 float* __restrict__ scores, int2* __restrict__ cand,
                 int* __restrict__ cnt, int M, int D, int CAP) {
    __shared__ float As[BK * ASTRIDE];   // ~12 KB, bank-swizzled row groups
    __shared__ float Bs[BK][BN];         // 16 KB

    const int tid = threadIdx.x;
    const int row0 = blockIdx.x * BM;
    const int col0 = blockIdx.y * BN;

    // A staging: 2 threads per row, 8 consecutive k each
    const int lr = tid >> 1;              // 0..127
    const int lh = (tid & 1) * 8;         // 0 or 8
    const int ag = lr >> 3;               // row group 0..15
    const int ao = lr & 7;                // within group
    const int arow = row0 + lr;

    // B staging: 1 thread per col, 16 k each
    const int bcol = col0 + tid;
    const bool bvalid = (bcol < M);
    const float binv = bvalid ? kinv[bcol] : 0.f;
    const float* brow = keys + (size_t)(bvalid ? bcol : 0) * D;

    // compute mapping: ty = low bits (16 distinct/wave, A swizzled -> 2-way free);
    //                  tx = high bits (4 distinct/wave -> B 2-way free)
    const int ty = tid & 15;              // rows ty*8 .. +8
    const int tx = tid >> 4;              // cols tx*16 .. +16

    float acc[8][16];
#pragma unroll
    for (int i = 0; i < 8; ++i)
#pragma unroll
        for (int j = 0; j < 16; ++j) acc[i][j] = 0.f;

    for (int k0 = 0; k0 < D; k0 += BK) {
        float4 a0 = *(const float4*)(xn + (size_t)arow * D + k0 + lh);
        float4 a1 = *(const float4*)(xn + (size_t)arow * D + k0 + lh + 4);
        float4 b0 = make_float4(0.f,0.f,0.f,0.f), b1 = b0, b2 = b0, b3 = b0;
        if (bvalid) {
            b0 = *(const float4*)(brow + k0);
            b1 = *(const float4*)(brow + k0 + 4);
            b2 = *(const float4*)(brow + k0 + 8);
            b3 = *(const float4*)(brow + k0 + 12);
        }
        __syncthreads();   // WAR guard vs previous iteration's reads
        {
            float av[8] = { a0.x, a0.y, a0.z, a0.w, a1.x, a1.y, a1.z, a1.w };
#pragma unroll
            for (int j = 0; j < 8; ++j)
                As[(lh + j) * ASTRIDE + ag * 12 + ao] = av[j];
            float bv[16] = { b0.x, b0.y, b0.z, b0.w, b1.x, b1.y, b1.z, b1.w,
                             b2.x, b2.y, b2.z, b2.w, b3.x, b3.y, b3.z, b3.w };
#pragma unroll
            for (int k = 0; k < 16; ++k)
                Bs[k][tid] = bv[k] * binv;
        }
        __syncthreads();

#pragma unroll
        for (int kk = 0; kk < BK; ++kk) {
            float4 af0 = *(const float4*)&As[kk * ASTRIDE + ty * 12];
            float4 af1 = *(const float4*)&As[kk * ASTRIDE + ty * 12 + 4];
            float4 bf0 = *(const float4*)&Bs[kk][tx * 16];
            float4 bf1 = *(const float4*)&Bs[kk][tx * 16 + 4];
            float4 bf2 = *(const float4*)&Bs[kk][tx * 16 + 8];
            float4 bf3 = *(const float4*)&Bs[kk][tx * 16 + 12];
            float a_[8] = { af0.x, af0.y, af0.z, af0.w, af1.x, af1.y, af1.z, af1.w };
            float b_[16] = { bf0.x, bf0.y, bf0.z, bf0.w, bf1.x, bf1.y, bf1.z, bf1.w,
                             bf2.x, bf2.y, bf2.z, bf2.w, bf3.x, bf3.y, bf3.z, bf3.w };
#pragma unroll
            for (int i = 0; i < 8; ++i)
#pragma unroll
                for (int j = 0; j < 16; ++j)
                    acc[i][j] += a_[i] * b_[j];
        }
    }

    // ---- epilogue: mask, store scores, collect candidates >= TAU ----
    const int cbase = col0 + tx * 16;
    bool cin[16];
    bool msk[16];
#pragma unroll
    for (int j = 0; j < 16; ++j) {
        int c = cbase + j;
        cin[j] = (c < M);
        msk[j] = cin[j] ? (values[c] == -1) : true;
    }
    const bool full = (cbase + 15 < M);
#pragma unroll
    for (int i = 0; i < 8; ++i) {
        int r = row0 + ty * 8 + i;
        float o[16];
#pragma unroll
        for (int j = 0; j < 16; ++j) o[j] = msk[j] ? NEG_INF_V : acc[i][j];
        if (full) {
            float* dst = scores + (size_t)r * M + cbase;
            *(float4*)(dst)      = make_float4(o[0], o[1], o[2], o[3]);
            *(float4*)(dst + 4)  = make_float4(o[4], o[5], o[6], o[7]);
            *(float4*)(dst + 8)  = make_float4(o[8], o[9], o[10], o[11]);
            *(float4*)(dst + 12) = make_float4(o[12], o[13], o[14], o[15]);
        } else {
#pragma unroll
            for (int j = 0; j < 16; ++j)
                if (cin[j]) scores[(size_t)r * M + cbase + j] = o[j];
        }
        if (CAP > 0) {
#pragma unroll
            for (int j = 0; j < 16; ++j) {
                if (cin[j] && o[j] >= TAU) {
                    int pos = atomicAdd(&cnt[r], 1);
                    if (pos < CAP) cand[(size_t)r * CAP + pos] =
                        make_int2(__float_as_int(o[j]), cbase + j);
                }
            }
        }
    }
}

// ---------------- selection: candidate fast path, histogram fallback ----------------
__device__ __forceinline__ int score_bin(float s) {
    float t = fminf(fmaxf((s + 1.0f) * 1024.0f, 0.0f), 2047.0f);
    return (int)t;
}

__global__ __launch_bounds__(256)
void select_kernel(const float* __restrict__ scores, const int* __restrict__ values,
                   const int* __restrict__ kptr, float* __restrict__ out,
                   const int2* __restrict__ cand, const int* __restrict__ cnt,
                   int M, int C, int CAP) {
    const int row = blockIdx.x;
    const int tid = threadIdx.x;
    const int K = *kptr;

    __shared__ float cs[SCAP];
    __shared__ int ci[SCAP];
    __shared__ int hist[NBINS];
    __shared__ float acc[32];
    __shared__ int scnt;
    __shared__ int tbin;

    if (tid < 32) acc[tid] = 0.f;
    __syncthreads();

    int n;
    const int n_all = cnt[row];
    if (CAP > 0 && n_all >= K && n_all <= CAP) {
        // fast path: candidates provably contain top-K (k-th largest >= TAU)
        n = n_all;
        for (int i = tid; i < n; i += 256) {
            int2 p = cand[(size_t)row * CAP + i];
            cs[i] = __int_as_float(p.x);
            ci[i] = p.y;
        }
        __syncthreads();
    } else {
        // fallback: exact histogram select on materialized scores
        for (int i = tid; i < NBINS; i += 256) hist[i] = 0;
        if (tid == 0) scnt = 0;
        __syncthreads();
        const float* srow = scores + (size_t)row * M;
        for (int m = tid; m < M; m += 256)
            atomicAdd(&hist[score_bin(srow[m])], 1);
        __syncthreads();
        if (tid < 64) {
            const int lane = tid;
            int csum = 0;
#pragma unroll
            for (int j = 0; j < NBINS / 64; ++j) csum += hist[lane * (NBINS / 64) + j];
            int sfx = csum;
#pragma unroll
            for (int off = 1; off < 64; off <<= 1) {
                int o = __shfl_down(sfx, off);
                if (lane + off < 64) sfx += o;
            }
            unsigned long long mask = __ballot(sfx >= K);
            int L = 63 - __builtin_clzll(mask);
            int above = (L == 63) ? 0 : __shfl(sfx, L + 1);
            if (lane == L) {
                int c = above;
                int t = L * (NBINS / 64);
                for (int j = NBINS / 64 - 1; j >= 0; --j) {
                    c += hist[L * (NBINS / 64) + j];
                    if (c >= K) { t = L * (NBINS / 64) + j; break; }
                }
                tbin = t;
            }
        }
        __syncthreads();
        const int T = tbin;
        for (int m = tid; m < M; m += 256) {
            float s = srow[m];
            if (score_bin(s) >= T) {
                int p = atomicAdd(&scnt, 1);
                if (p < SCAP) { cs[p] = s; ci[p] = m; }
            }
        }
        __syncthreads();
        n = scnt < SCAP ? scnt : SCAP;
    }

    // exact rank among candidates (lax.top_k tie order: lower index wins)
    for (int i = tid; i < n; i += 256) {
        float s = cs[i];
        int idx = ci[i];
        int rank = 0;
        for (int j = 0; j < n; ++j) {
            float sj = cs[j];
            rank += (sj > s) || (sj == s && ci[j] < idx);
        }
        if (rank < K) {
            int lbl = values[idx];
            if (lbl >= 0) atomicAdd(&acc[lbl], s);
        }
    }
    __syncthreads();
    if (tid < C) out[(size_t)row * C + tid] = acc[tid];
}

extern "C" void kernel_launch(void* const* d_in, const int* in_sizes, int n_in,
                              void* d_out, int out_size, void* d_ws, size_t ws_size,
                              hipStream_t stream) {
    const float* x = (const float*)d_in[0];
    const float* keys = (const float*)d_in[1];
    const int* values = (const int*)d_in[2];
    const int* kptr = (const int*)d_in[3];
    float* out = (float*)d_out;

    const int M = in_sizes[2];            // 60000
    const int D = in_sizes[1] / M;        // 512
    const int B = in_sizes[0] / D;        // 1024
    const int C = out_size / B;           // 10

    float* xn = (float*)d_ws;                               // B*D floats
    float* kinv = xn + (size_t)B * D;                       // M floats
    float* scores = kinv + (size_t)M;                       // B*M floats
    size_t base_f = (size_t)B * D + M + (size_t)B * M;
    int* cnt = (int*)(xn + base_f);                         // B ints
    int2* cand = (int2*)(cnt + B);                          // B*CAP int2

    size_t used = base_f * sizeof(float) + (size_t)B * sizeof(int);
    size_t avail = (ws_size > used) ? (ws_size - used) : 0;
    int CAP = (int)((avail / ((size_t)B * sizeof(int2))) < (size_t)SCAP
                        ? (avail / ((size_t)B * sizeof(int2)))
                        : (size_t)SCAP);
    if (CAP < 64) CAP = 0;

    hipMemsetAsync(cnt, 0, (size_t)B * sizeof(int), stream);

    xnorm_kernel<<<B, 64, 0, stream>>>(x, xn, D);
    kinv_kernel<<<(M + 3) / 4, 256, 0, stream>>>(keys, kinv, M, D);

    dim3 ggrid(B / BM, (M + BN - 1) / BN);                  // row-tiles fastest -> key-tile L2 reuse
    gemm_kernel<<<ggrid, 256, 0, stream>>>(xn, keys, kinv, values, scores,
                                           cand, cnt, M, D, CAP);

    select_kernel<<<B, 256, 0, stream>>>(scores, values, kptr, out, cand, cnt, M, C, CAP);
}

// Round 3
// 1213.903 us; speedup vs baseline: 1.0754x; 1.0754x over previous
//
#include <hip/hip_runtime.h>
#include <math.h>

#define BM 128
#define BN 128
#define BK 16
#define BRS 140                        // swizzled B row stride (floats)
#define BPOS(c) ((c) + ((((unsigned)(c)) >> 5) << 2))   // pad-swizzle: +4 floats per 32
#define EPSV 1e-12f
#define NEG_INF_V -1000000000.0f
#define NBINS 2048
#define SCAP 2048
#define CAP 2048
#define TAU 0.10f

// ---------------- normalize x rows (one wave per row) ----------------
__global__ void xnorm_kernel(const float* __restrict__ x, float* __restrict__ xn, int D) {
    int row = blockIdx.x;
    int lane = threadIdx.x;
    const float4* xr = (const float4*)(x + (size_t)row * D);
    float4* xo = (float4*)(xn + (size_t)row * D);
    int per = (D / 4) / 64;
    float ss = 0.f;
    float4 v[4];
    for (int i = 0; i < per; ++i) {
        float4 t = xr[lane * per + i];
        v[i] = t;
        ss += t.x * t.x + t.y * t.y + t.z * t.z + t.w * t.w;
    }
    for (int off = 32; off >= 1; off >>= 1) ss += __shfl_xor(ss, off);
    float denom = fmaxf(sqrtf(ss), EPSV);
    for (int i = 0; i < per; ++i) {
        float4 t = v[i];
        t.x /= denom; t.y /= denom; t.z /= denom; t.w /= denom;
        xo[lane * per + i] = t;
    }
}

// ---------------- key inverse norms (one wave per key row) ----------------
__global__ void kinv_kernel(const float* __restrict__ keys, float* __restrict__ kinv,
                            int M, int D) {
    int wave = threadIdx.x >> 6;
    int lane = threadIdx.x & 63;
    int row = blockIdx.x * 4 + wave;
    if (row >= M) return;
    const float4* kr = (const float4*)(keys + (size_t)row * D);
    int per = (D / 4) / 64;
    float ss = 0.f;
    for (int i = 0; i < per; ++i) {
        float4 t = kr[lane * per + i];
        ss += t.x * t.x + t.y * t.y + t.z * t.z + t.w * t.w;
    }
    for (int off = 32; off >= 1; off >>= 1) ss += __shfl_xor(ss, off);
    if (lane == 0) kinv[row] = 1.0f / fmaxf(sqrtf(ss), EPSV);
}

// ---------------- fp32 SGEMM 128x128, 8x8/thread, swizzled Bs, no score store ----------------
__global__ __launch_bounds__(256, 2)
void gemm_kernel(const float* __restrict__ xn, const float* __restrict__ keys,
                 const float* __restrict__ kinv, const int* __restrict__ values,
                 int2* __restrict__ cand, int* __restrict__ cnt, int M, int D) {
    __shared__ float As[BK][BM];
    __shared__ float Bs[BK * BRS];

    const int tid = threadIdx.x;
    const int row0 = blockIdx.x * BM;
    const int col0 = blockIdx.y * BN;

    // staging: 2 threads per tile-row, 8 consecutive k each
    const int lr = tid >> 1;              // 0..127
    const int lh = (tid & 1) * 8;         // 0 or 8
    const int arow = row0 + lr;
    const int bcol = col0 + lr;
    const bool bvalid = (bcol < M);
    const float binv = bvalid ? kinv[bcol] : 0.f;
    const float* brow = keys + (size_t)(bvalid ? bcol : 0) * D;

    const int tx = tid & 15;              // col group (8 cols)
    const int ty = tid >> 4;              // row group (8 rows)
    const int bbase0 = tx * 8 + ((tx >> 2) << 2);   // BPOS(tx*8)

    float acc[8][8];
#pragma unroll
    for (int i = 0; i < 8; ++i)
#pragma unroll
        for (int j = 0; j < 8; ++j) acc[i][j] = 0.f;

    for (int k0 = 0; k0 < D; k0 += BK) {
        float4 a0 = *(const float4*)(xn + (size_t)arow * D + k0 + lh);
        float4 a1 = *(const float4*)(xn + (size_t)arow * D + k0 + lh + 4);
        float4 b0 = make_float4(0.f, 0.f, 0.f, 0.f), b1 = b0;
        if (bvalid) {
            b0 = *(const float4*)(brow + k0 + lh);
            b1 = *(const float4*)(brow + k0 + lh + 4);
        }
        __syncthreads();   // WAR guard vs previous iteration's reads
        {
            float av[8] = { a0.x, a0.y, a0.z, a0.w, a1.x, a1.y, a1.z, a1.w };
            float bv[8] = { b0.x, b0.y, b0.z, b0.w, b1.x, b1.y, b1.z, b1.w };
            const int bp = BPOS(lr);
#pragma unroll
            for (int j = 0; j < 8; ++j) {
                As[lh + j][lr] = av[j];
                Bs[(lh + j) * BRS + bp] = bv[j] * binv;
            }
        }
        __syncthreads();

#pragma unroll
        for (int kk = 0; kk < BK; ++kk) {
            float4 af0 = *(const float4*)&As[kk][ty * 8];
            float4 af1 = *(const float4*)&As[kk][ty * 8 + 4];
            float4 bf0 = *(const float4*)&Bs[kk * BRS + bbase0];
            float4 bf1 = *(const float4*)&Bs[kk * BRS + bbase0 + 4];
            float a_[8] = { af0.x, af0.y, af0.z, af0.w, af1.x, af1.y, af1.z, af1.w };
            float b_[8] = { bf0.x, bf0.y, bf0.z, bf0.w, bf1.x, bf1.y, bf1.z, bf1.w };
#pragma unroll
            for (int i = 0; i < 8; ++i)
#pragma unroll
                for (int j = 0; j < 8; ++j)
                    acc[i][j] += a_[i] * b_[j];
        }
    }

    // ---- epilogue: collect candidates >= TAU (no score materialization) ----
    const int cbase = col0 + tx * 8;
    bool ok[8];
#pragma unroll
    for (int j = 0; j < 8; ++j) {
        int c = cbase + j;
        ok[j] = (c < M) && (values[c] != -1);
    }
#pragma unroll
    for (int i = 0; i < 8; ++i) {
        int r = row0 + ty * 8 + i;
#pragma unroll
        for (int j = 0; j < 8; ++j) {
            float s = acc[i][j];
            if (ok[j] && s >= TAU) {
                int pos = atomicAdd(&cnt[r], 1);
                if (pos < CAP) cand[(size_t)r * CAP + pos] =
                    make_int2(__float_as_int(s), cbase + j);
            }
        }
    }
}

// ---------------- fast select: exact rank among collected candidates ----------------
__global__ __launch_bounds__(256)
void select_fast(const int* __restrict__ values, const int* __restrict__ kptr,
                 float* __restrict__ out, const int2* __restrict__ cand,
                 const int* __restrict__ cnt, int C) {
    const int row = blockIdx.x;
    const int tid = threadIdx.x;
    const int K = *kptr;
    const int n = cnt[row];
    if (n < K || n > CAP) return;         // uniform branch; fallback kernel owns this row

    __shared__ float cs[CAP];
    __shared__ int ci[CAP];
    __shared__ float acc[32];

    if (tid < 32) acc[tid] = 0.f;
    for (int i = tid; i < n; i += 256) {
        int2 p = cand[(size_t)row * CAP + i];
        cs[i] = __int_as_float(p.x);
        ci[i] = p.y;
    }
    __syncthreads();

    for (int i = tid; i < n; i += 256) {
        float s = cs[i];
        int idx = ci[i];
        int rank = 0;
        for (int j = 0; j < n; ++j) {
            float sj = cs[j];
            rank += (sj > s) || (sj == s && ci[j] < idx);   // lax.top_k tie order
        }
        if (rank < K) {
            int lbl = values[idx];
            if (lbl >= 0) atomicAdd(&acc[lbl], s);
        }
    }
    __syncthreads();
    if (tid < C) out[(size_t)row * C + tid] = acc[tid];
}

// ---------------- exact fallback: recompute row scores on the fly (cold path) ----------------
__device__ __forceinline__ int score_bin(float s) {
    float t = fminf(fmaxf((s + 1.0f) * 1024.0f, 0.0f), 2047.0f);
    return (int)t;
}

__global__ __launch_bounds__(256)
void fallback_kernel(const float* __restrict__ xn, const float* __restrict__ keys,
                     const float* __restrict__ kinv, const int* __restrict__ values,
                     const int* __restrict__ kptr, float* __restrict__ out,
                     const int* __restrict__ cnt, int M, int D, int C) {
    const int row = blockIdx.x;
    const int tid = threadIdx.x;
    const int K = *kptr;
    const int n_all = cnt[row];
    if (n_all >= K && n_all <= CAP) return;   // fast path owned it

    __shared__ float xrow[512];
    __shared__ int hist[NBINS];
    __shared__ float cs[SCAP];
    __shared__ int ci[SCAP];
    __shared__ float acc[32];
    __shared__ int scnt;
    __shared__ int tbin;

    for (int d = tid; d < D; d += 256) xrow[d] = xn[(size_t)row * D + d];
    for (int i = tid; i < NBINS; i += 256) hist[i] = 0;
    if (tid == 0) scnt = 0;
    if (tid < 32) acc[tid] = 0.f;
    __syncthreads();

    // pass 1: histogram
    for (int m = tid; m < M; m += 256) {
        float s;
        if (values[m] == -1) s = NEG_INF_V;
        else {
            const float4* kr = (const float4*)(keys + (size_t)m * D);
            float ss = 0.f;
            for (int d4 = 0; d4 < D / 4; ++d4) {
                float4 t = kr[d4];
                const float4* xq = (const float4*)&xrow[d4 * 4];
                ss += t.x * xq->x + t.y * xq->y + t.z * xq->z + t.w * xq->w;
            }
            s = ss * kinv[m];
        }
        atomicAdd(&hist[score_bin(s)], 1);
    }
    __syncthreads();

    if (tid < 64) {
        const int lane = tid;
        int csum = 0;
#pragma unroll
        for (int j = 0; j < NBINS / 64; ++j) csum += hist[lane * (NBINS / 64) + j];
        int sfx = csum;
#pragma unroll
        for (int off = 1; off < 64; off <<= 1) {
            int o = __shfl_down(sfx, off);
            if (lane + off < 64) sfx += o;
        }
        unsigned long long mask = __ballot(sfx >= K);
        int L = 63 - __builtin_clzll(mask);
        int above = (L == 63) ? 0 : __shfl(sfx, L + 1);
        if (lane == L) {
            int c = above;
            int t = L * (NBINS / 64);
            for (int j = NBINS / 64 - 1; j >= 0; --j) {
                c += hist[L * (NBINS / 64) + j];
                if (c >= K) { t = L * (NBINS / 64) + j; break; }
            }
            tbin = t;
        }
    }
    __syncthreads();

    // pass 2: recompute + collect
    const int T = tbin;
    for (int m = tid; m < M; m += 256) {
        float s;
        if (values[m] == -1) s = NEG_INF_V;
        else {
            const float4* kr = (const float4*)(keys + (size_t)m * D);
            float ss = 0.f;
            for (int d4 = 0; d4 < D / 4; ++d4) {
                float4 t = kr[d4];
                const float4* xq = (const float4*)&xrow[d4 * 4];
                ss += t.x * xq->x + t.y * xq->y + t.z * xq->z + t.w * xq->w;
            }
            s = ss * kinv[m];
        }
        if (score_bin(s) >= T) {
            int p = atomicAdd(&scnt, 1);
            if (p < SCAP) { cs[p] = s; ci[p] = m; }
        }
    }
    __syncthreads();

    int n = scnt < SCAP ? scnt : SCAP;
    for (int i = tid; i < n; i += 256) {
        float s = cs[i];
        int idx = ci[i];
        int rank = 0;
        for (int j = 0; j < n; ++j) {
            float sj = cs[j];
            rank += (sj > s) || (sj == s && ci[j] < idx);
        }
        if (rank < K) {
            int lbl = values[idx];
            if (lbl >= 0) atomicAdd(&acc[lbl], s);
        }
    }
    __syncthreads();
    if (tid < C) out[(size_t)row * C + tid] = acc[tid];
}

extern "C" void kernel_launch(void* const* d_in, const int* in_sizes, int n_in,
                              void* d_out, int out_size, void* d_ws, size_t ws_size,
                              hipStream_t stream) {
    const float* x = (const float*)d_in[0];
    const float* keys = (const float*)d_in[1];
    const int* values = (const int*)d_in[2];
    const int* kptr = (const int*)d_in[3];
    float* out = (float*)d_out;

    const int M = in_sizes[2];            // 60000
    const int D = in_sizes[1] / M;        // 512
    const int B = in_sizes[0] / D;        // 1024
    const int C = out_size / B;           // 10

    float* xn = (float*)d_ws;                               // B*D floats
    float* kinv = xn + (size_t)B * D;                       // M floats
    int* cnt = (int*)(kinv + M);                            // B ints
    int2* cand = (int2*)(cnt + B);                          // B*CAP int2 (~16.8 MB total ws)

    hipMemsetAsync(cnt, 0, (size_t)B * sizeof(int), stream);

    xnorm_kernel<<<B, 64, 0, stream>>>(x, xn, D);
    kinv_kernel<<<(M + 3) / 4, 256, 0, stream>>>(keys, kinv, M, D);

    dim3 ggrid(B / BM, (M + BN - 1) / BN);                  // row-tiles fastest -> key-tile L2 reuse
    gemm_kernel<<<ggrid, 256, 0, stream>>>(xn, keys, kinv, values, cand, cnt, M, D);

    select_fast<<<B, 256, 0, stream>>>(values, kptr, out, cand, cnt, C);
    fallback_kernel<<<B, 256, 0, stream>>>(xn, keys, kinv, values, kptr, out, cnt, M, D, C);
}

// Round 4
// 938.354 us; speedup vs baseline: 1.3912x; 1.2937x over previous
//
#include <hip/hip_runtime.h>
#include <math.h>

#define BM 128
#define BN 128
#define BK 16
#define EPSV 1e-12f
#define NEG_INF_V -1000000000.0f
#define NBINS 2048          // fallback histogram bins over [-1,1]
#define FBINS 1024          // fast-path fine bins over [TAU, TAU+0.2)
#define FSCALE 5120.0f      // 1024 / 0.2
#define SCAP 2048
#define CAP 2048
#define SSCAP 1024
#define TAU 0.10f

// ---------------- normalize x rows (one wave per row) ----------------
__global__ void xnorm_kernel(const float* __restrict__ x, float* __restrict__ xn, int D) {
    int row = blockIdx.x;
    int lane = threadIdx.x;
    const float4* xr = (const float4*)(x + (size_t)row * D);
    float4* xo = (float4*)(xn + (size_t)row * D);
    int per = (D / 4) / 64;
    float ss = 0.f;
    float4 v[4];
    for (int i = 0; i < per; ++i) {
        float4 t = xr[lane * per + i];
        v[i] = t;
        ss += t.x * t.x + t.y * t.y + t.z * t.z + t.w * t.w;
    }
    for (int off = 32; off >= 1; off >>= 1) ss += __shfl_xor(ss, off);
    float denom = fmaxf(sqrtf(ss), EPSV);
    for (int i = 0; i < per; ++i) {
        float4 t = v[i];
        t.x /= denom; t.y /= denom; t.z /= denom; t.w /= denom;
        xo[lane * per + i] = t;
    }
}

// ---------------- key inverse norms (one wave per key row) ----------------
__global__ void kinv_kernel(const float* __restrict__ keys, float* __restrict__ kinv,
                            int M, int D) {
    int wave = threadIdx.x >> 6;
    int lane = threadIdx.x & 63;
    int row = blockIdx.x * 4 + wave;
    if (row >= M) return;
    const float4* kr = (const float4*)(keys + (size_t)row * D);
    int per = (D / 4) / 64;
    float ss = 0.f;
    for (int i = 0; i < per; ++i) {
        float4 t = kr[lane * per + i];
        ss += t.x * t.x + t.y * t.y + t.z * t.z + t.w * t.w;
    }
    for (int off = 32; off >= 1; off >>= 1) ss += __shfl_xor(ss, off);
    if (lane == 0) kinv[row] = 1.0f / fmaxf(sqrtf(ss), EPSV);
}

// ---- fp32 SGEMM 128x128, 8x8/thread, dbuf LDS + register prefetch, candidate epilogue ----
__global__ __launch_bounds__(256, 2)
void gemm_kernel(const float* __restrict__ xn, const float* __restrict__ keys,
                 const float* __restrict__ kinv, const int* __restrict__ values,
                 int2* __restrict__ cand, int* __restrict__ cnt, int M, int D) {
    __shared__ float As[2][BK][BM];
    __shared__ float Bs[2][BK][BN];

    const int tid = threadIdx.x;
    const int row0 = blockIdx.x * BM;
    const int col0 = blockIdx.y * BN;

    // staging: 2 threads per tile-row, 8 consecutive k each
    const int lr = tid >> 1;
    const int lh = (tid & 1) * 8;
    const int arow = row0 + lr;
    const int bcol = col0 + lr;
    const bool bvalid = (bcol < M);
    const float binv = bvalid ? kinv[bcol] : 0.f;
    const float* ap = xn + (size_t)arow * D + lh;
    const float* bp = keys + (size_t)(bvalid ? bcol : 0) * D + lh;

    const int tx = tid & 15;
    const int ty = tid >> 4;

    float acc[8][8];
#pragma unroll
    for (int i = 0; i < 8; ++i)
#pragma unroll
        for (int j = 0; j < 8; ++j) acc[i][j] = 0.f;

    // prefetch tile 0 into registers
    float4 a0 = *(const float4*)(ap);
    float4 a1 = *(const float4*)(ap + 4);
    float4 b0 = make_float4(0.f, 0.f, 0.f, 0.f), b1 = b0;
    if (bvalid) { b0 = *(const float4*)(bp); b1 = *(const float4*)(bp + 4); }

    // stage tile 0 into buffer 0
    {
        float av[8] = { a0.x, a0.y, a0.z, a0.w, a1.x, a1.y, a1.z, a1.w };
        float bv[8] = { b0.x, b0.y, b0.z, b0.w, b1.x, b1.y, b1.z, b1.w };
#pragma unroll
        for (int j = 0; j < 8; ++j) {
            As[0][lh + j][lr] = av[j];
            Bs[0][lh + j][lr] = bv[j] * binv;
        }
    }

    int cur = 0;
    for (int k0 = 0; k0 < D; k0 += BK) {
        __syncthreads();                       // buffer `cur` fully staged for all waves
        const bool more = (k0 + BK) < D;
        if (more) {                            // issue next tile's loads early: hidden by fma loop
            a0 = *(const float4*)(ap + k0 + BK);
            a1 = *(const float4*)(ap + k0 + BK + 4);
            if (bvalid) {
                b0 = *(const float4*)(bp + k0 + BK);
                b1 = *(const float4*)(bp + k0 + BK + 4);
            }
        }

#pragma unroll
        for (int kk = 0; kk < BK; ++kk) {
            float4 af0 = *(const float4*)&As[cur][kk][ty * 8];
            float4 af1 = *(const float4*)&As[cur][kk][ty * 8 + 4];
            float4 bf0 = *(const float4*)&Bs[cur][kk][tx * 8];
            float4 bf1 = *(const float4*)&Bs[cur][kk][tx * 8 + 4];
            float a_[8] = { af0.x, af0.y, af0.z, af0.w, af1.x, af1.y, af1.z, af1.w };
            float b_[8] = { bf0.x, bf0.y, bf0.z, bf0.w, bf1.x, bf1.y, bf1.z, bf1.w };
#pragma unroll
            for (int i = 0; i < 8; ++i)
#pragma unroll
                for (int j = 0; j < 8; ++j)
                    acc[i][j] += a_[i] * b_[j];
        }

        if (more) {                            // stage next tile into the other buffer
            int nxt = cur ^ 1;
            float av[8] = { a0.x, a0.y, a0.z, a0.w, a1.x, a1.y, a1.z, a1.w };
            float bv[8] = { b0.x, b0.y, b0.z, b0.w, b1.x, b1.y, b1.z, b1.w };
#pragma unroll
            for (int j = 0; j < 8; ++j) {
                As[nxt][lh + j][lr] = av[j];
                Bs[nxt][lh + j][lr] = bv[j] * binv;
            }
            cur = nxt;
        }
    }

    // ---- epilogue: collect candidates >= TAU ----
    const int cbase = col0 + tx * 8;
    bool ok[8];
#pragma unroll
    for (int j = 0; j < 8; ++j) {
        int c = cbase + j;
        ok[j] = (c < M) && (values[c] != -1);
    }
#pragma unroll
    for (int i = 0; i < 8; ++i) {
        int r = row0 + ty * 8 + i;
#pragma unroll
        for (int j = 0; j < 8; ++j) {
            float s = acc[i][j];
            if (ok[j] && s >= TAU) {
                int pos = atomicAdd(&cnt[r], 1);
                if (pos < CAP) cand[(size_t)r * CAP + pos] =
                    make_int2(__float_as_int(s), cbase + j);
            }
        }
    }
}

// ---------------- selection: fine-histogram filter + small exact rank ----------------
__device__ __forceinline__ int fbin(float s) {
    return (int)fminf((s - TAU) * FSCALE, (float)(FBINS - 1));   // s >= TAU guaranteed
}
__device__ __forceinline__ int score_bin(float s) {
    float t = fminf(fmaxf((s + 1.0f) * 1024.0f, 0.0f), 2047.0f);
    return (int)t;
}

__global__ __launch_bounds__(256)
void select_kernel(const float* __restrict__ xn, const float* __restrict__ keys,
                   const float* __restrict__ kinv, const int* __restrict__ values,
                   const int* __restrict__ kptr, float* __restrict__ out,
                   const int2* __restrict__ cand, const int* __restrict__ cnt,
                   int M, int D, int C) {
    const int row = blockIdx.x;
    const int tid = threadIdx.x;
    const int K = *kptr;

    __shared__ float cs[SCAP];
    __shared__ int ci[SCAP];
    __shared__ int hist[NBINS];
    __shared__ float ss[SSCAP];
    __shared__ int si[SSCAP];
    __shared__ float xrow[512];
    __shared__ float accs[32];
    __shared__ int scnt, mcnt, tb;

    const int n0 = cnt[row];
    bool fast = (n0 >= K && n0 <= CAP);      // block-uniform
    int m = 0;

    if (tid < 32) accs[tid] = 0.f;
    if (tid == 0) { scnt = 0; mcnt = 0; }

    if (fast) {
        for (int i = tid; i < FBINS; i += 256) hist[i] = 0;
        __syncthreads();
        for (int i = tid; i < n0; i += 256) {
            int2 p = cand[(size_t)row * CAP + i];
            float s = __int_as_float(p.x);
            cs[i] = s; ci[i] = p.y;
            atomicAdd(&hist[fbin(s)], 1);
        }
        __syncthreads();
        if (tid < 64) {                       // suffix over 64 chunks of 16 bins
            const int lane = tid;
            int csum = 0;
#pragma unroll
            for (int j = 0; j < FBINS / 64; ++j) csum += hist[lane * (FBINS / 64) + j];
            int sfx = csum;
#pragma unroll
            for (int off = 1; off < 64; off <<= 1) {
                int o = __shfl_down(sfx, off);
                if (lane + off < 64) sfx += o;
            }
            unsigned long long mask = __ballot(sfx >= K);
            int L = 63 - __builtin_clzll(mask);
            int above = (L == 63) ? 0 : __shfl(sfx, L + 1);
            if (lane == L) {
                int c = above;
                int t = L * (FBINS / 64);
                for (int j = FBINS / 64 - 1; j >= 0; --j) {
                    c += hist[L * (FBINS / 64) + j];
                    if (c >= K) { t = L * (FBINS / 64) + j; break; }
                }
                tb = t;
            }
        }
        __syncthreads();
        const int T = tb;
        for (int i = tid; i < n0; i += 256) {
            if (fbin(cs[i]) >= T) {
                int p = atomicAdd(&mcnt, 1);
                if (p < SSCAP) { ss[p] = cs[i]; si[p] = ci[i]; }
            }
        }
        __syncthreads();
        m = mcnt;
        if (m > SSCAP) fast = false;          // statistically impossible; exact fallback
    }

    if (!fast) {
        // cold path: recompute row scores, histogram select (exact)
        for (int d = tid; d < D; d += 256) xrow[d] = xn[(size_t)row * D + d];
        for (int i = tid; i < NBINS; i += 256) hist[i] = 0;
        __syncthreads();
        for (int mm = tid; mm < M; mm += 256) {
            float s;
            if (values[mm] == -1) s = NEG_INF_V;
            else {
                const float4* kr = (const float4*)(keys + (size_t)mm * D);
                float sum = 0.f;
                for (int d4 = 0; d4 < D / 4; ++d4) {
                    float4 t = kr[d4];
                    const float4* xq = (const float4*)&xrow[d4 * 4];
                    sum += t.x * xq->x + t.y * xq->y + t.z * xq->z + t.w * xq->w;
                }
                s = sum * kinv[mm];
            }
            atomicAdd(&hist[score_bin(s)], 1);
        }
        __syncthreads();
        if (tid < 64) {
            const int lane = tid;
            int csum = 0;
#pragma unroll
            for (int j = 0; j < NBINS / 64; ++j) csum += hist[lane * (NBINS / 64) + j];
            int sfx = csum;
#pragma unroll
            for (int off = 1; off < 64; off <<= 1) {
                int o = __shfl_down(sfx, off);
                if (lane + off < 64) sfx += o;
            }
            unsigned long long mask = __ballot(sfx >= K);
            int L = 63 - __builtin_clzll(mask);
            int above = (L == 63) ? 0 : __shfl(sfx, L + 1);
            if (lane == L) {
                int c = above;
                int t = L * (NBINS / 64);
                for (int j = NBINS / 64 - 1; j >= 0; --j) {
                    c += hist[L * (NBINS / 64) + j];
                    if (c >= K) { t = L * (NBINS / 64) + j; break; }
                }
                tb = t;
            }
        }
        __syncthreads();
        const int T = tb;
        for (int mm = tid; mm < M; mm += 256) {
            float s;
            if (values[mm] == -1) s = NEG_INF_V;
            else {
                const float4* kr = (const float4*)(keys + (size_t)mm * D);
                float sum = 0.f;
                for (int d4 = 0; d4 < D / 4; ++d4) {
                    float4 t = kr[d4];
                    const float4* xq = (const float4*)&xrow[d4 * 4];
                    sum += t.x * xq->x + t.y * xq->y + t.z * xq->z + t.w * xq->w;
                }
                s = sum * kinv[mm];
            }
            if (score_bin(s) >= T) {
                int p = atomicAdd(&scnt, 1);
                if (p < SCAP) { cs[p] = s; ci[p] = mm; }
            }
        }
        __syncthreads();
        m = scnt < SCAP ? scnt : SCAP;
    }

    const float* rs = fast ? ss : cs;
    const int* ri = fast ? si : ci;
    for (int i = tid; i < m; i += 256) {
        float s = rs[i];
        int idx = ri[i];
        int rank = 0;
        for (int j = 0; j < m; ++j) {
            float sj = rs[j];
            rank += (sj > s) || (sj == s && ri[j] < idx);   // lax.top_k tie order
        }
        if (rank < K) {
            int lbl = values[idx];
            if (lbl >= 0) atomicAdd(&accs[lbl], s);
        }
    }
    __syncthreads();
    if (tid < C) out[(size_t)row * C + tid] = accs[tid];
}

extern "C" void kernel_launch(void* const* d_in, const int* in_sizes, int n_in,
                              void* d_out, int out_size, void* d_ws, size_t ws_size,
                              hipStream_t stream) {
    const float* x = (const float*)d_in[0];
    const float* keys = (const float*)d_in[1];
    const int* values = (const int*)d_in[2];
    const int* kptr = (const int*)d_in[3];
    float* out = (float*)d_out;

    const int M = in_sizes[2];            // 60000
    const int D = in_sizes[1] / M;        // 512
    const int B = in_sizes[0] / D;        // 1024
    const int C = out_size / B;           // 10

    float* xn = (float*)d_ws;                               // B*D floats
    float* kinv = xn + (size_t)B * D;                       // M floats
    int* cnt = (int*)(kinv + M);                            // B ints
    int2* cand = (int2*)(cnt + B);                          // B*CAP int2

    hipMemsetAsync(cnt, 0, (size_t)B * sizeof(int), stream);

    xnorm_kernel<<<B, 64, 0, stream>>>(x, xn, D);
    kinv_kernel<<<(M + 3) / 4, 256, 0, stream>>>(keys, kinv, M, D);

    dim3 ggrid(B / BM, (M + BN - 1) / BN);                  // row-tiles fastest -> key-tile L2 reuse
    gemm_kernel<<<ggrid, 256, 0, stream>>>(xn, keys, kinv, values, cand, cnt, M, D);

    select_kernel<<<B, 256, 0, stream>>>(xn, keys, kinv, values, kptr, out,
                                         cand, cnt, M, D, C);
}

// Round 5
// 814.634 us; speedup vs baseline: 1.6025x; 1.1519x over previous
//
#include <hip/hip_runtime.h>
#include <math.h>

#define BM 128
#define BN 128
#define EPSV 1e-12f
#define NEG_INF_V -1000000000.0f
#define NBINS 2048
#define FBINS 1024
#define FSCALE 5120.0f
#define SCAP 2048
#define CAP 2048
#define SSCAP 1024
#define TAU 0.10f

typedef __attribute__((ext_vector_type(8))) short bf16x8;
typedef __attribute__((ext_vector_type(4))) float f32x4;

__device__ __forceinline__ unsigned short f2bf(float f) {
    unsigned int u = __float_as_uint(f);
    unsigned int r = (u + 0x7fffu + ((u >> 16) & 1u)) >> 16;
    return (unsigned short)r;
}
__device__ __forceinline__ float bf2f(unsigned short h) {
    return __uint_as_float(((unsigned int)h) << 16);
}
__device__ __forceinline__ void split3(float v, unsigned short& h0,
                                       unsigned short& h1, unsigned short& h2) {
    h0 = f2bf(v); float r = v - bf2f(h0);
    h1 = f2bf(r); r -= bf2f(h1);
    h2 = f2bf(r);
}
__device__ __forceinline__ void gload_lds16(const unsigned short* g, const unsigned short* l) {
    __builtin_amdgcn_global_load_lds((const __attribute__((address_space(1))) void*)g,
                                     (__attribute__((address_space(3))) void*)l, 16, 0, 0);
}

// ---------------- normalize x rows (one wave per row) ----------------
__global__ void xnorm_kernel(const float* __restrict__ x, float* __restrict__ xn, int D) {
    int row = blockIdx.x;
    int lane = threadIdx.x;
    const float4* xr = (const float4*)(x + (size_t)row * D);
    float4* xo = (float4*)(xn + (size_t)row * D);
    int per = (D / 4) / 64;
    float ss = 0.f;
    float4 v[4];
    for (int i = 0; i < per; ++i) {
        float4 t = xr[lane * per + i];
        v[i] = t;
        ss += t.x * t.x + t.y * t.y + t.z * t.z + t.w * t.w;
    }
    for (int off = 32; off >= 1; off >>= 1) ss += __shfl_xor(ss, off);
    float denom = fmaxf(sqrtf(ss), EPSV);
    for (int i = 0; i < per; ++i) {
        float4 t = v[i];
        t.x /= denom; t.y /= denom; t.z /= denom; t.w /= denom;
        xo[lane * per + i] = t;
    }
}

// ---------------- key inverse norms (one wave per key row) ----------------
__global__ void kinv_kernel(const float* __restrict__ keys, float* __restrict__ kinv,
                            int M, int D) {
    int wave = threadIdx.x >> 6;
    int lane = threadIdx.x & 63;
    int row = blockIdx.x * 4 + wave;
    if (row >= M) return;
    const float4* kr = (const float4*)(keys + (size_t)row * D);
    int per = (D / 4) / 64;
    float ss = 0.f;
    for (int i = 0; i < per; ++i) {
        float4 t = kr[lane * per + i];
        ss += t.x * t.x + t.y * t.y + t.z * t.z + t.w * t.w;
    }
    for (int off = 32; off >= 1; off >>= 1) ss += __shfl_xor(ss, off);
    if (lane == 0) kinv[row] = 1.0f / fmaxf(sqrtf(ss), EPSV);
}

// ---------------- split xn into 3 bf16 planes (row-major) ----------------
__global__ void xsplit_kernel(const float* __restrict__ xn, unsigned short* __restrict__ X0,
                              unsigned short* __restrict__ X1, unsigned short* __restrict__ X2,
                              int total4) {
    int e = blockIdx.x * 256 + threadIdx.x;
    if (e >= total4) return;
    float4 v = ((const float4*)xn)[e];
    unsigned short h0[4], h1[4], h2[4];
    split3(v.x, h0[0], h1[0], h2[0]);
    split3(v.y, h0[1], h1[1], h2[1]);
    split3(v.z, h0[2], h1[2], h2[2]);
    split3(v.w, h0[3], h1[3], h2[3]);
    ((ushort4*)X0)[e] = make_ushort4(h0[0], h0[1], h0[2], h0[3]);
    ((ushort4*)X1)[e] = make_ushort4(h1[0], h1[1], h1[2], h1[3]);
    ((ushort4*)X2)[e] = make_ushort4(h2[0], h2[1], h2[2], h2[3]);
}

// ------- split keys*kinv into 3 bf16 planes, packed per (col-tile, k-chunk) in
// ------- fragment order with XOR bank swizzle: slot[tau][mp][qp] = row tau*16+mp,
// ------- k-octet (qp ^ (mp&3)). One block per (ct, t); 512 slots of 8 bf16.
__global__ __launch_bounds__(256)
void ksplit_kernel(const float* __restrict__ keys, const float* __restrict__ kinv,
                   unsigned short* __restrict__ K0, unsigned short* __restrict__ K1,
                   unsigned short* __restrict__ K2, int M, int D, int nk) {
    const int ct = blockIdx.x / nk;
    const int t  = blockIdx.x % nk;
    const size_t blk = (size_t)blockIdx.x * 4096;   // shorts
#pragma unroll
    for (int half = 0; half < 2; ++half) {
        int sig = half * 256 + threadIdx.x;         // slot 0..511
        int tau = sig >> 6;
        int mp  = (sig >> 2) & 15;
        int qp  = sig & 3;
        int row = ct * 128 + tau * 16 + mp;
        int qs  = qp ^ (mp & 3);
        unsigned short h0[8], h1[8], h2[8];
        if (row < M) {
            float inv = kinv[row];
            const float* src = keys + (size_t)row * D + t * 32 + qs * 8;
#pragma unroll
            for (int i = 0; i < 8; ++i) split3(src[i] * inv, h0[i], h1[i], h2[i]);
        } else {
#pragma unroll
            for (int i = 0; i < 8; ++i) { h0[i] = 0; h1[i] = 0; h2[i] = 0; }
        }
        size_t off = blk + (size_t)sig * 8;
        *(bf16x8*)(K0 + off) = *(bf16x8*)h0;
        *(bf16x8*)(K1 + off) = *(bf16x8*)h1;
        *(bf16x8*)(K2 + off) = *(bf16x8*)h2;
    }
}

// ---------------- MFMA GEMM: 128x128 block, 4 waves 2x2, 6 split-products ----------------
__global__ __launch_bounds__(256, 2)
void gemm_kernel(const unsigned short* __restrict__ Xs,   // 3 planes, stride xplane
                 const unsigned short* __restrict__ Kp,   // 3 packed planes, stride kplane
                 const int* __restrict__ values,
                 int2* __restrict__ cand, int* __restrict__ cnt,
                 int M, int D, int nk, size_t xplane, size_t kplane) {
    __shared__ unsigned short Bs[2][3 * 4096];   // 2 x 24 KB

    const int tid  = threadIdx.x;
    const int lane = tid & 63;
    const int w    = tid >> 6;
    const int wx   = w >> 1, wy = w & 1;
    const int rt   = blockIdx.x;                 // 0..7
    const int ct   = blockIdx.y;                 // 0..nct-1
    const int row0 = rt * BM, col0 = ct * BN;
    const int mq   = lane & 15;
    const int qd   = lane >> 4;
    const int bswz = mq * 32 + ((qd ^ (mq & 3)) << 3);   // B-frag intra-tile short offset

    f32x4 acc[4][4];
#pragma unroll
    for (int i = 0; i < 4; ++i)
#pragma unroll
        for (int j = 0; j < 4; ++j) acc[i][j] = (f32x4){0.f, 0.f, 0.f, 0.f};

    // stage chunk t of the 3 K-planes into Bs[buf]: 24 wave-slices of 1 KB
#define STAGE(t_, buf_)                                                          \
    {                                                                            \
        const size_t blk_ = ((size_t)ct * nk + (t_)) * 4096;                     \
        _Pragma("unroll")                                                        \
        for (int i_ = 0; i_ < 6; ++i_) {                                         \
            int s_ = w + i_ * 4;                                                 \
            int sp_ = s_ >> 3, pt_ = s_ & 7;                                     \
            gload_lds16(Kp + (size_t)sp_ * kplane + blk_ + pt_ * 512 + lane * 8, \
                        &Bs[buf_][sp_ * 4096 + pt_ * 512]);                      \
        }                                                                        \
    }

    STAGE(0, 0);

    for (int t = 0; t < nk; ++t) {
        const int buf = t & 1;
        __syncthreads();                          // drains staging of chunk t

        // A fragments for chunk t, straight from L2-resident split planes
        bf16x8 af[3][4];
#pragma unroll
        for (int s = 0; s < 3; ++s)
#pragma unroll
            for (int ta = 0; ta < 4; ++ta) {
                int arow = row0 + wx * 64 + ta * 16 + mq;
                af[s][ta] = *(const bf16x8*)(Xs + (size_t)s * xplane +
                                             (size_t)arow * D + t * 32 + qd * 8);
            }

        if (t + 1 < nk) STAGE(t + 1, buf ^ 1);

#pragma unroll
        for (int sb = 0; sb < 3; ++sb) {
            bf16x8 bfr[4];
#pragma unroll
            for (int tb = 0; tb < 4; ++tb)
                bfr[tb] = *(const bf16x8*)&Bs[buf][sb * 4096 + (wy * 4 + tb) * 512 + bswz];
#pragma unroll
            for (int sa = 0; sa < 3; ++sa) {
                if (sa + sb <= 2) {               // pairs 00,01,10,11,02,20
#pragma unroll
                    for (int ta = 0; ta < 4; ++ta)
#pragma unroll
                        for (int tb = 0; tb < 4; ++tb)
                            acc[ta][tb] = __builtin_amdgcn_mfma_f32_16x16x32_bf16(
                                af[sa][ta], bfr[tb], acc[ta][tb], 0, 0, 0);
                }
            }
        }
    }

    // ---- epilogue: candidate collection (C/D layout: col=lane&15, row=(lane>>4)*4+reg) ----
    int ncol[4]; bool okn[4];
#pragma unroll
    for (int tb = 0; tb < 4; ++tb) {
        int n = col0 + wy * 64 + tb * 16 + mq;
        ncol[tb] = n;
        okn[tb] = (n < M) && (values[n] != -1);
    }
#pragma unroll
    for (int ta = 0; ta < 4; ++ta) {
        int rbase = row0 + wx * 64 + ta * 16 + qd * 4;
#pragma unroll
        for (int tb = 0; tb < 4; ++tb) {
            if (!okn[tb]) continue;
#pragma unroll
            for (int rg = 0; rg < 4; ++rg) {
                float s = acc[ta][tb][rg];
                if (s >= TAU) {
                    int r = rbase + rg;
                    int pos = atomicAdd(&cnt[r], 1);
                    if (pos < CAP) cand[(size_t)r * CAP + pos] =
                        make_int2(__float_as_int(s), ncol[tb]);
                }
            }
        }
    }
#undef STAGE
}

// ---------------- selection: fine-histogram filter + small exact rank ----------------
__device__ __forceinline__ int fbin(float s) {
    return (int)fminf((s - TAU) * FSCALE, (float)(FBINS - 1));
}
__device__ __forceinline__ int score_bin(float s) {
    float t = fminf(fmaxf((s + 1.0f) * 1024.0f, 0.0f), 2047.0f);
    return (int)t;
}

__global__ __launch_bounds__(256)
void select_kernel(const float* __restrict__ xn, const float* __restrict__ keys,
                   const float* __restrict__ kinv, const int* __restrict__ values,
                   const int* __restrict__ kptr, float* __restrict__ out,
                   const int2* __restrict__ cand, const int* __restrict__ cnt,
                   int M, int D, int C) {
    const int row = blockIdx.x;
    const int tid = threadIdx.x;
    const int K = *kptr;

    __shared__ float cs[SCAP];
    __shared__ int ci[SCAP];
    __shared__ int hist[NBINS];
    __shared__ float ss[SSCAP];
    __shared__ int si[SSCAP];
    __shared__ float xrow[512];
    __shared__ float accs[32];
    __shared__ int scnt, mcnt, tb;

    const int n0 = cnt[row];
    bool fast = (n0 >= K && n0 <= CAP);
    int m = 0;

    if (tid < 32) accs[tid] = 0.f;
    if (tid == 0) { scnt = 0; mcnt = 0; }

    if (fast) {
        for (int i = tid; i < FBINS; i += 256) hist[i] = 0;
        __syncthreads();
        for (int i = tid; i < n0; i += 256) {
            int2 p = cand[(size_t)row * CAP + i];
            float s = __int_as_float(p.x);
            cs[i] = s; ci[i] = p.y;
            atomicAdd(&hist[fbin(s)], 1);
        }
        __syncthreads();
        if (tid < 64) {
            const int lane = tid;
            int csum = 0;
#pragma unroll
            for (int j = 0; j < FBINS / 64; ++j) csum += hist[lane * (FBINS / 64) + j];
            int sfx = csum;
#pragma unroll
            for (int off = 1; off < 64; off <<= 1) {
                int o = __shfl_down(sfx, off);
                if (lane + off < 64) sfx += o;
            }
            unsigned long long mask = __ballot(sfx >= K);
            int L = 63 - __builtin_clzll(mask);
            int above = (L == 63) ? 0 : __shfl(sfx, L + 1);
            if (lane == L) {
                int c = above;
                int t = L * (FBINS / 64);
                for (int j = FBINS / 64 - 1; j >= 0; --j) {
                    c += hist[L * (FBINS / 64) + j];
                    if (c >= K) { t = L * (FBINS / 64) + j; break; }
                }
                tb = t;
            }
        }
        __syncthreads();
        const int T = tb;
        for (int i = tid; i < n0; i += 256) {
            if (fbin(cs[i]) >= T) {
                int p = atomicAdd(&mcnt, 1);
                if (p < SSCAP) { ss[p] = cs[i]; si[p] = ci[i]; }
            }
        }
        __syncthreads();
        m = mcnt;
        if (m > SSCAP) fast = false;
    }

    if (!fast) {
        for (int d = tid; d < D; d += 256) xrow[d] = xn[(size_t)row * D + d];
        for (int i = tid; i < NBINS; i += 256) hist[i] = 0;
        __syncthreads();
        for (int mm = tid; mm < M; mm += 256) {
            float s;
            if (values[mm] == -1) s = NEG_INF_V;
            else {
                const float4* kr = (const float4*)(keys + (size_t)mm * D);
                float sum = 0.f;
                for (int d4 = 0; d4 < D / 4; ++d4) {
                    float4 t = kr[d4];
                    const float4* xq = (const float4*)&xrow[d4 * 4];
                    sum += t.x * xq->x + t.y * xq->y + t.z * xq->z + t.w * xq->w;
                }
                s = sum * kinv[mm];
            }
            atomicAdd(&hist[score_bin(s)], 1);
        }
        __syncthreads();
        if (tid < 64) {
            const int lane = tid;
            int csum = 0;
#pragma unroll
            for (int j = 0; j < NBINS / 64; ++j) csum += hist[lane * (NBINS / 64) + j];
            int sfx = csum;
#pragma unroll
            for (int off = 1; off < 64; off <<= 1) {
                int o = __shfl_down(sfx, off);
                if (lane + off < 64) sfx += o;
            }
            unsigned long long mask = __ballot(sfx >= K);
            int L = 63 - __builtin_clzll(mask);
            int above = (L == 63) ? 0 : __shfl(sfx, L + 1);
            if (lane == L) {
                int c = above;
                int t = L * (NBINS / 64);
                for (int j = NBINS / 64 - 1; j >= 0; --j) {
                    c += hist[L * (NBINS / 64) + j];
                    if (c >= K) { t = L * (NBINS / 64) + j; break; }
                }
                tb = t;
            }
        }
        __syncthreads();
        const int T = tb;
        for (int mm = tid; mm < M; mm += 256) {
            float s;
            if (values[mm] == -1) s = NEG_INF_V;
            else {
                const float4* kr = (const float4*)(keys + (size_t)mm * D);
                float sum = 0.f;
                for (int d4 = 0; d4 < D / 4; ++d4) {
                    float4 t = kr[d4];
                    const float4* xq = (const float4*)&xrow[d4 * 4];
                    sum += t.x * xq->x + t.y * xq->y + t.z * xq->z + t.w * xq->w;
                }
                s = sum * kinv[mm];
            }
            if (score_bin(s) >= T) {
                int p = atomicAdd(&scnt, 1);
                if (p < SCAP) { cs[p] = s; ci[p] = mm; }
            }
        }
        __syncthreads();
        m = scnt < SCAP ? scnt : SCAP;
    }

    const float* rs = fast ? ss : cs;
    const int* ri = fast ? si : ci;
    for (int i = tid; i < m; i += 256) {
        float s = rs[i];
        int idx = ri[i];
        int rank = 0;
        for (int j = 0; j < m; ++j) {
            float sj = rs[j];
            rank += (sj > s) || (sj == s && ri[j] < idx);
        }
        if (rank < K) {
            int lbl = values[idx];
            if (lbl >= 0) atomicAdd(&accs[lbl], s);
        }
    }
    __syncthreads();
    if (tid < C) out[(size_t)row * C + tid] = accs[tid];
}

extern "C" void kernel_launch(void* const* d_in, const int* in_sizes, int n_in,
                              void* d_out, int out_size, void* d_ws, size_t ws_size,
                              hipStream_t stream) {
    const float* x = (const float*)d_in[0];
    const float* keys = (const float*)d_in[1];
    const int* values = (const int*)d_in[2];
    const int* kptr = (const int*)d_in[3];
    float* out = (float*)d_out;

    const int M = in_sizes[2];            // 60000
    const int D = in_sizes[1] / M;        // 512
    const int B = in_sizes[0] / D;        // 1024
    const int C = out_size / B;           // 10
    const int nk = D / 32;                // 16 k-chunks
    const int nct = (M + BN - 1) / BN;    // 469 col tiles
    const size_t xplane = (size_t)B * D;              // shorts per X plane
    const size_t kplane = (size_t)nct * nk * 4096;    // shorts per packed K plane

    char* wp = (char*)d_ws;
    float* xn = (float*)wp;                wp += (size_t)B * D * 4;
    float* kinv = (float*)wp;              wp += ((size_t)M * 4 + 255) / 256 * 256;
    int* cnt = (int*)wp;                   wp += (size_t)B * 4;
    int2* cand = (int2*)wp;                wp += (size_t)B * CAP * 8;
    unsigned short* Xs = (unsigned short*)wp;  wp += 3 * xplane * 2;   // 3 planes contiguous
    unsigned short* K0 = (unsigned short*)wp;  wp += kplane * 2;
    unsigned short* K1 = (unsigned short*)wp;  wp += kplane * 2;
    unsigned short* K2 = (unsigned short*)wp;

    hipMemsetAsync(cnt, 0, (size_t)B * sizeof(int), stream);

    xnorm_kernel<<<B, 64, 0, stream>>>(x, xn, D);
    kinv_kernel<<<(M + 3) / 4, 256, 0, stream>>>(keys, kinv, M, D);
    xsplit_kernel<<<(B * D / 4 + 255) / 256, 256, 0, stream>>>(
        xn, Xs, Xs + xplane, Xs + 2 * xplane, B * D / 4);
    ksplit_kernel<<<nct * nk, 256, 0, stream>>>(keys, kinv, K0, K1, K2, M, D, nk);

    dim3 ggrid(B / BM, nct);
    gemm_kernel<<<ggrid, 256, 0, stream>>>(Xs, K0, values, cand, cnt,
                                           M, D, nk, xplane, kplane);

    select_kernel<<<B, 256, 0, stream>>>(xn, keys, kinv, values, kptr, out,
                                         cand, cnt, M, D, C);
}